// Round 11
// baseline (477.137 us; speedup 1.0000x reference)
//
#include <hip/hip_runtime.h>
#include <hip/hip_bf16.h>

// Sizes (fixed by the reference)
//  V=32000, T=48, E=128, HID=256, H=128, B=256, L=512, 4H=512
typedef unsigned short ushort_t;
typedef unsigned int uint_t;
typedef __bf16 bf16x8 __attribute__((ext_vector_type(8)));
typedef float f32x4 __attribute__((ext_vector_type(4)));

#define L2E 1.44269504088896340736f
#define LN2 0.69314718055994530942f

// LDS-only barrier: does NOT drain vmcnt -> global loads/stores stay in flight.
#define WGBAR() __asm__ volatile("s_waitcnt lgkmcnt(0)\n\ts_barrier" ::: "memory")

static __device__ __forceinline__ float fexp2(float x) { return __builtin_amdgcn_exp2f(x); }
static __device__ __forceinline__ float flog2(float x) { return __builtin_amdgcn_logf(x); }
static __device__ __forceinline__ float frcp (float x) { return __builtin_amdgcn_rcpf(x); }

static __device__ __forceinline__ float sigm(float x) {
  return frcp(1.0f + fexp2(-L2E * x));
}
static __device__ __forceinline__ float tanha(float x) {
  return 1.0f - 2.0f * frcp(1.0f + fexp2(2.0f * L2E * x));
}

// Hardware bf16 pair-convert (RNE). result = bf16(lo) | bf16(hi)<<16.
static __device__ __forceinline__ uint_t cvtpk(float lo, float hi) {
  uint_t r;
  asm("v_cvt_pk_bf16_f32 %0, %1, %2" : "=v"(r) : "v"(lo), "v"(hi));
  return r;
}
static __device__ __forceinline__ bf16x8 pack8(float4 a, float4 b) {
  uint4 u = make_uint4(cvtpk(a.x, a.y), cvtpk(a.z, a.w),
                       cvtpk(b.x, b.y), cvtpk(b.z, b.w));
  return __builtin_bit_cast(bf16x8, u);
}
static __device__ __forceinline__ uint2 pack4(float4 a) {
  return make_uint2(cvtpk(a.x, a.y), cvtpk(a.z, a.w));
}

// DPP row-rotate-right by K within 16-lane rows (K=0 -> identity).
template <int K>
static __device__ __forceinline__ float rotk(float x) {
  if constexpr (K == 0) {
    return x;
  } else {
    return __builtin_bit_cast(float, __builtin_amdgcn_update_dpp(
        0, __builtin_bit_cast(int, x), 0x120 + K, 0xf, 0xf, true));
  }
}
static __device__ __forceinline__ float bperf(int addr, int val) {
  return __builtin_bit_cast(float, __builtin_amdgcn_ds_bpermute(addr, val));
}

// ---------------------------------------------------------------------------
// K2 v10 (unchanged from round 10 -- measured-good ~307 us). CONTROL.
// ---------------------------------------------------------------------------
__global__ __launch_bounds__(512, 2) void k2_lstm(
    const int* __restrict__ words, const float* __restrict__ emb,
    const float* __restrict__ Wih_f, const float* __restrict__ Whh_f,
    const float* __restrict__ bih_f, const float* __restrict__ bhh_f,
    const float* __restrict__ Wih_b, const float* __restrict__ Whh_b,
    const float* __restrict__ bih_b, const float* __restrict__ bhh_b,
    ushort_t* __restrict__ hT, float* __restrict__ loss_out) {
  const int wg = blockIdx.x;
  const int dir = wg >> 7;
  const int r0 = (wg & 127) << 1;
  if (wg == 0 && threadIdx.x == 0) loss_out[0] = 0.f;
  const float* Whh = dir ? Whh_b : Whh_f;
  const float* Wih = dir ? Wih_b : Wih_f;
  const float* bih = dir ? bih_b : bih_f;
  const float* bhh = dir ? bhh_b : bhh_f;

  const int tid = threadIdx.x;
  const int w = tid >> 6;        // wave 0..7
  const int lane = tid & 63;
  const int l15 = lane & 15;
  const int kq = lane >> 4;      // 0..3

  __shared__ __align__(16) ushort_t hx[2][2][136];      //  1,088 B
  __shared__ __align__(16) ushort_t xp[2][16][128][4];  // 32,768 B
  __shared__ __align__(16) ushort_t xs[2][16][136];     //  8,704 B

  bf16x8 wfh[4][4], wfx[4][4];
  float biasP[4];
#pragma unroll
  for (int Q = 0; Q < 4; ++Q) {
    const int n = Q * 128 + w * 16 + l15;
    biasP[Q] = bih[n] + bhh[n];
#pragma unroll
    for (int c = 0; c < 4; ++c) {
      const int k0 = c * 32 + kq * 8;
      const float* sh = Whh + n * 128 + k0;
      const float* sx = Wih + n * 128 + k0;
      wfh[Q][c] = pack8(*(const float4*)sh, *(const float4*)(sh + 4));
      wfx[Q][c] = pack8(*(const float4*)sx, *(const float4*)(sx + 4));
    }
  }

  const int ur = (lane >> 4) & 1;
  const int uj = w * 16 + l15;
  float cst = 0.f;
  const f32x4 fz = {0.f, 0.f, 0.f, 0.f};

  const int sm = tid >> 5;
  const int sc = (tid & 31) * 4;
  const int str = r0 + (sm & 1);
  const int stl = sm >> 1;

  uint_t pd0[4], pd1[4];
  f32x4 pc = {0.f, 0.f, 0.f, 0.f};
  f32x4 pcsv = {0.f, 0.f, 0.f, 0.f};

  if (tid < 256) hx[0][tid >> 7][tid & 127] = 0;
  {
    const int tg = stl;
    const int tf = dir ? (511 - tg) : tg;
    const int word = words[str * 512 + tf];
    float4 av = *(const float4*)(emb + (size_t)word * 128 + sc);
    *(uint2*)&xs[1][sm][sc] = pack4(av);
  }
  WGBAR();
  {
    f32x4 qv[4];
#pragma unroll
    for (int Q = 0; Q < 4; ++Q) {
      f32x4 pc0 = {biasP[Q], biasP[Q], biasP[Q], biasP[Q]};
#pragma unroll
      for (int c = 0; c < 4; ++c) {
        bf16x8 af = __builtin_bit_cast(bf16x8, *(const uint4*)&xs[1][l15][kq * 8 + c * 32]);
        pc0 = __builtin_amdgcn_mfma_f32_16x16x32_bf16(af, wfx[Q][c], pc0, 0, 0, 0);
      }
      qv[Q] = pc0;
    }
#pragma unroll
    for (int rr = 0; rr < 4; ++rr) {
      pd0[rr] = cvtpk(qv[0][rr], qv[1][rr]);
      pd1[rr] = cvtpk(qv[2][rr], qv[3][rr]);
      *(uint2*)&xp[0][kq * 4 + rr][uj][0] = make_uint2(pd0[rr], pd1[rr]);
    }
  }
  {
    const int tg = 8 + stl;
    const int tf = dir ? (511 - tg) : tg;
    const int word = words[str * 512 + tf];
    float4 av = *(const float4*)(emb + (size_t)word * 128 + sc);
    *(uint2*)&xs[0][sm][sc] = pack4(av);
  }
  WGBAR();

  int sword = 0;
  float4 se0 = make_float4(0.f, 0.f, 0.f, 0.f);

#pragma unroll 1
  for (int i = 0; i < 64; ++i) {
    const int pcon = i & 1;
    const int ppro = pcon ^ 1;
    bf16x8 afp[4];
    if (i < 63) {
#pragma unroll
      for (int c = 0; c < 4; ++c)
        afp[c] = __builtin_bit_cast(bf16x8, *(const uint4*)&xs[pcon][l15][kq * 8 + c * 32]);
    }
#pragma unroll
    for (int s = 0; s < 8; ++s) {
      const int t = i * 8 + s;
      const int p = t & 1;
      const uint2 xq = *(const uint2*)&xp[pcon][2 * s + ur][uj][0];
      if (i < 62) {
        if (s == 0) {
          const int tg = (i + 2) * 8 + stl;
          const int tf = dir ? (511 - tg) : tg;
          sword = words[str * 512 + tf];
        }
        if (s == 2) se0 = *(const float4*)(emb + (size_t)sword * 128 + sc);
        if (s == 6) *(uint2*)&xs[ppro][sm][sc] = pack4(se0);
      }
      f32x4 a0, a1, a2, a3;
      const ushort_t* abase = &hx[p][l15 & 1][kq * 8];
      {
        bf16x8 af = __builtin_bit_cast(bf16x8, *(const uint4*)(abase));
        a0 = __builtin_amdgcn_mfma_f32_16x16x32_bf16(af, wfh[0][0], fz, 0, 0, 0);
        a1 = __builtin_amdgcn_mfma_f32_16x16x32_bf16(af, wfh[1][0], fz, 0, 0, 0);
        a2 = __builtin_amdgcn_mfma_f32_16x16x32_bf16(af, wfh[2][0], fz, 0, 0, 0);
        a3 = __builtin_amdgcn_mfma_f32_16x16x32_bf16(af, wfh[3][0], fz, 0, 0, 0);
      }
#pragma unroll
      for (int c = 1; c < 4; ++c) {
        bf16x8 af = __builtin_bit_cast(bf16x8, *(const uint4*)(abase + c * 32));
        a0 = __builtin_amdgcn_mfma_f32_16x16x32_bf16(af, wfh[0][c], a0, 0, 0, 0);
        a1 = __builtin_amdgcn_mfma_f32_16x16x32_bf16(af, wfh[1][c], a1, 0, 0, 0);
        a2 = __builtin_amdgcn_mfma_f32_16x16x32_bf16(af, wfh[2][c], a2, 0, 0, 0);
        a3 = __builtin_amdgcn_mfma_f32_16x16x32_bf16(af, wfh[3][c], a3, 0, 0, 0);
      }
      if (i < 63) {
        const int Q = s >> 1;
        if ((s & 1) == 0) {
          pc = f32x4{biasP[Q], biasP[Q], biasP[Q], biasP[Q]};
          pc = __builtin_amdgcn_mfma_f32_16x16x32_bf16(afp[0], wfx[Q][0], pc, 0, 0, 0);
          pc = __builtin_amdgcn_mfma_f32_16x16x32_bf16(afp[1], wfx[Q][1], pc, 0, 0, 0);
        } else {
          pc = __builtin_amdgcn_mfma_f32_16x16x32_bf16(afp[2], wfx[Q][2], pc, 0, 0, 0);
          pc = __builtin_amdgcn_mfma_f32_16x16x32_bf16(afp[3], wfx[Q][3], pc, 0, 0, 0);
          if ((s & 2) == 0) {
            pcsv = pc;
          } else if (s == 3) {
#pragma unroll
            for (int rr = 0; rr < 4; ++rr) pd0[rr] = cvtpk(pcsv[rr], pc[rr]);
          } else {
#pragma unroll
            for (int rr = 0; rr < 4; ++rr) {
              pd1[rr] = cvtpk(pcsv[rr], pc[rr]);
              *(uint2*)&xp[ppro][kq * 4 + rr][uj][0] = make_uint2(pd0[rr], pd1[rr]);
            }
          }
        }
      }
      const float g0 = (ur ? a0[1] : a0[0]) + __builtin_bit_cast(float, xq.x << 16);
      const float g1 = (ur ? a1[1] : a1[0]) + __builtin_bit_cast(float, xq.x & 0xffff0000u);
      const float g2 = (ur ? a2[1] : a2[0]) + __builtin_bit_cast(float, xq.y << 16);
      const float g3 = (ur ? a3[1] : a3[0]) + __builtin_bit_cast(float, xq.y & 0xffff0000u);
      const float si = sigm(g0), sf = sigm(g1), so = sigm(g3);
      const float tg = tanha(g2);
      cst = sf * cst + si * tg;
      const float h = so * tanha(cst);
      const ushort_t hb = (ushort_t)cvtpk(h, h);
      if (lane < 32) {
        hx[p ^ 1][ur][uj] = hb;
        const int tf = dir ? (511 - t) : t;
        hT[((size_t)(r0 + ur) * 512 + tf) * 256 + (dir << 7) + uj] = hb;
      }
      WGBAR();
    }
  }
}

// ---------------------------------------------------------------------------
// K4 v14: both CRF chains interleaved in ONE wave (latency-hiding probe +
// win-if-true), 48-slot gather (3 ds_bpermute of rows 0..2 + 48 DPP-fmacs;
// the old m-slot whose sources were rows 48-63 was all-zero coefficients).
// wave0 = alpha (fwd t=1..255, maskless) + beta (bwd t=511..256, masked),
// step-interleaved so the two independent dataflows hide each other's
// stalls. wave1 = pure producer: emis tiles for BOTH ends produced
// CONCURRENTLY with wave0's serial phase (produce leaves the wall), plus
// the gold-path numerator. Phase-boundary Ecur refresh avoids reading the
// tile being produced (the last in-phase body's look-ahead is discarded).
// ---------------------------------------------------------------------------
#define ROTMOD_0  ""
#define ROTMOD_1  "row_ror:1 row_mask:0xf bank_mask:0xf"
#define ROTMOD_2  "row_ror:2 row_mask:0xf bank_mask:0xf"
#define ROTMOD_3  "row_ror:3 row_mask:0xf bank_mask:0xf"
#define ROTMOD_4  "row_ror:4 row_mask:0xf bank_mask:0xf"
#define ROTMOD_5  "row_ror:5 row_mask:0xf bank_mask:0xf"
#define ROTMOD_6  "row_ror:6 row_mask:0xf bank_mask:0xf"
#define ROTMOD_7  "row_ror:7 row_mask:0xf bank_mask:0xf"
#define ROTMOD_8  "row_ror:8 row_mask:0xf bank_mask:0xf"
#define ROTMOD_9  "row_ror:9 row_mask:0xf bank_mask:0xf"
#define ROTMOD_10 "row_ror:10 row_mask:0xf bank_mask:0xf"
#define ROTMOD_11 "row_ror:11 row_mask:0xf bank_mask:0xf"
#define ROTMOD_12 "row_ror:12 row_mask:0xf bank_mask:0xf"
#define ROTMOD_13 "row_ror:13 row_mask:0xf bank_mask:0xf"
#define ROTMOD_14 "row_ror:14 row_mask:0xf bank_mask:0xf"
#define ROTMOD_15 "row_ror:15 row_mask:0xf bank_mask:0xf"

#define K4_ROW16(OP, m) \
  OP(m, 0) OP(m, 1) OP(m, 2) OP(m, 3) OP(m, 4) OP(m, 5) OP(m, 6) OP(m, 7) \
  OP(m, 8) OP(m, 9) OP(m, 10) OP(m, 11) OP(m, 12) OP(m, 13) OP(m, 14) OP(m, 15)
#define K4_S48(OP) K4_ROW16(OP, 0) K4_ROW16(OP, 1) K4_ROW16(OP, 2)

#define K4_FMA_A(m_, k_) asm( \
    "v_fmac_f32 %0, %1, %2 " ROTMOD_##k_ \
    : "+v"(acc[((m_) * 16 + (k_)) & 7]) \
    : "v"(dm##m_), "v"(pcr_a[(m_) * 16 + (k_)]));
#define K4_FMA_B(m_, k_) asm( \
    "v_fmac_f32 %0, %1, %2 " ROTMOD_##k_ \
    : "+v"(acc[((m_) * 16 + (k_)) & 7]) \
    : "v"(dm##m_), "v"(pcr_b[(m_) * 16 + (k_)]));

// emis tile reads (A: tile p in tA[p&1]; B: tile tau in tB[(tau&1)^1])
#define EMA(tt) tA[((tt) >> 6) & 1][(tt) & 63][jj]
#define EMB(tt) tB[((((tt) >> 6) & 1)) ^ 1][(tt) & 63][jj]

// alpha step (no masks below t=256: lengths >= 256 per input spec)
#define A_BODY(FOLD, TN, MEAS)                                                \
  {                                                                           \
    float E = Ecur_a;                                                         \
    if (FOLD) {                                                               \
      E *= __builtin_bit_cast(float, (uint_t)(127 - ep_a) << 23);             \
      S_a += ep_a;                                                            \
    }                                                                         \
    const float emn_ = EMA(TN);                                               \
    const int di_ = __builtin_bit_cast(int, d_a);                             \
    float dm0 = bperf(ba0, di_);                                              \
    float dm1 = bperf(ba1, di_);                                              \
    float dm2 = bperf(ba2, di_);                                              \
    float acc[8] = {0.f, 0.f, 0.f, 0.f, 0.f, 0.f, 0.f, 0.f};                  \
    K4_S48(K4_FMA_A)                                                          \
    d_a = (((acc[0] + acc[1]) + (acc[2] + acc[3])) +                          \
           ((acc[4] + acc[5]) + (acc[6] + acc[7]))) * E;                      \
    if (MEAS) {                                                               \
      const int db_ =                                                         \
          __builtin_amdgcn_readfirstlane(__builtin_bit_cast(int, d_a));       \
      ep_a = ((db_ >> 23) & 0xff) - 127;                                      \
    }                                                                         \
    Ecur_a = fexp2(emn_ * L2E);                                               \
  }

// beta step: y <- P @ (E_t o y) when masked-in
#define B_BODY(FOLD, TN, MBIT, MEAS)                                          \
  {                                                                           \
    float E = Ecur_b;                                                         \
    int eApp = 0;                                                             \
    if (FOLD) {                                                               \
      E *= __builtin_bit_cast(float, (uint_t)(127 - ep_b) << 23);             \
      eApp = ep_b;                                                            \
    }                                                                         \
    const float emn_ = EMB(TN);                                               \
    const float vs_ = E * d_b;                                                \
    const int di_ = __builtin_bit_cast(int, vs_);                             \
    float dm0 = bperf(ba0, di_);                                              \
    float dm1 = bperf(ba1, di_);                                              \
    float dm2 = bperf(ba2, di_);                                              \
    float acc[8] = {0.f, 0.f, 0.f, 0.f, 0.f, 0.f, 0.f, 0.f};                  \
    K4_S48(K4_FMA_B)                                                          \
    const float nxt_ = (((acc[0] + acc[1]) + (acc[2] + acc[3])) +             \
                        ((acc[4] + acc[5]) + (acc[6] + acc[7])));             \
    if (MBIT) { d_b = nxt_; S_b += eApp; }                                    \
    if (MEAS) {                                                               \
      const int db_ =                                                         \
          __builtin_amdgcn_readfirstlane(__builtin_bit_cast(int, d_b));       \
      ep_b = ((db_ >> 23) & 0xff) - 127;                                      \
    }                                                                         \
    Ecur_b = fexp2(emn_ * L2E);                                               \
  }

// one interleaved group: 8 alpha steps (t=G..G+7) + 8 beta steps (t=T0..T0-7)
#define GROUP_PAIR(G, T0, MM)                                                 \
  A_BODY(false, (G) + 1, true)                                                \
  B_BODY(false, (T0) - 1, ((MM) >> 7) & 1u, true)                             \
  A_BODY(false, (G) + 2, false)                                               \
  B_BODY(false, (T0) - 2, ((MM) >> 6) & 1u, false)                            \
  A_BODY(true,  (G) + 3, false)                                               \
  B_BODY(true,  (T0) - 3, ((MM) >> 5) & 1u, false)                            \
  A_BODY(false, (G) + 4, false)                                               \
  B_BODY(false, (T0) - 4, ((MM) >> 4) & 1u, false)                            \
  A_BODY(false, (G) + 5, false)                                               \
  B_BODY(false, (T0) - 5, ((MM) >> 3) & 1u, false)                            \
  A_BODY(false, (G) + 6, false)                                               \
  B_BODY(false, (T0) - 6, ((MM) >> 2) & 1u, false)                            \
  A_BODY(false, (G) + 7, false)                                               \
  B_BODY(false, (T0) - 7, ((MM) >> 1) & 1u, false)                            \
  A_BODY(false, ALAST, false)                                                 \
  B_BODY(false, BLAST, ((MM) >> 0) & 1u, false)

__global__ __launch_bounds__(128, 1) void k4_fused(
    const int* __restrict__ words, const int* __restrict__ tags,
    const ushort_t* __restrict__ hT, const float* __restrict__ Wout,
    const float* __restrict__ bout, const float* __restrict__ trans,
    const float* __restrict__ st, const float* __restrict__ et,
    float* __restrict__ out) {
  const int b = blockIdx.x;
  const int tid = threadIdx.x;
  const int wv = tid >> 6;       // wave 0 = dual serial chains, wave 1 = producer
  const int lane = tid & 63;
  const int l15 = lane & 15;
  const int kq = lane >> 4;

  __shared__ __align__(16) ushort_t wfrag[3][8][64][8];  // 24,576 B
  __shared__ float tA[2][64][50];                        // 25,600 B
  __shared__ float tB[2][64][50];                        // 25,600 B
  __shared__ float res1[1];

  const ushort_t* hb_base = hT + (size_t)b * 512 * 256;
  const int j = lane;
  const bool v = j < 48;
  const int jj = v ? j : 47;

  // bpermute byte-addresses for source rows 0..2 (lane 16*s + (j&15))
  const int ba0 = 4 * (0 * 16 + l15);
  const int ba1 = 4 * (1 * 16 + l15);
  const int ba2 = 4 * (2 * 16 + l15);

  float bo3[3];
#pragma unroll
  for (int jt = 0; jt < 3; ++jt) bo3[jt] = bout[jt * 16 + l15];

  // ---- wave0: dual gather calibration + beta masks; wave1: wfrag build ----
  float pcr_a[48], pcr_b[48];
  unsigned long long mq4 = 0, mq5 = 0, mq6 = 0, mq7 = 0;
  if (wv == 0) {
    const int pj = __builtin_bit_cast(int, (float)j);
    float pm0 = bperf(ba0, pj);
    float pm1 = bperf(ba1, pj);
    float pm2 = bperf(ba2, pj);
#define K4_CALA(m, k) { const int idx_ = (int)rotk<k>(pm##m); \
    pcr_a[(m) * 16 + (k)] = (v && idx_ < 48) ? fexp2(trans[idx_ * 48 + j] * L2E) : 0.f; }
    K4_S48(K4_CALA)
#undef K4_CALA
#define K4_CALB(m, k) { const int idx_ = (int)rotk<k>(pm##m); \
    pcr_b[(m) * 16 + (k)] = (v && idx_ < 48) ? fexp2(trans[j * 48 + idx_] * L2E) : 0.f; }
    K4_S48(K4_CALB)
#undef K4_CALB
    mq4 = __ballot(words[b * 512 + 4 * 64 + lane] != 0);
    mq5 = __ballot(words[b * 512 + 5 * 64 + lane] != 0);
    mq6 = __ballot(words[b * 512 + 6 * 64 + lane] != 0);
    mq7 = __ballot(words[b * 512 + 7 * 64 + lane] != 0);
  } else {
#pragma unroll 1
    for (int f = 0; f < 24; ++f) {
      const int jt = f / 8, c = f & 7;
      const float* src = Wout + (jt * 16 + l15) * 256 + c * 32 + kq * 8;
      bf16x8 fr = pack8(*(const float4*)src, *(const float4*)(src + 4));
      *(uint4*)&wfrag[jt][c][lane][0] = __builtin_bit_cast(uint4, fr);
    }
  }
  __syncthreads();   // wfrag ready

  // ---- producer: one 64-t emis tile ----
  auto produce = [&](int tile, float (*dst)[50]) {
#pragma unroll
    for (int ts = 0; ts < 4; ++ts) {
      const int tt0 = tile * 64 + ts * 16;
      bf16x8 afr[8];
#pragma unroll
      for (int c = 0; c < 8; ++c)
        afr[c] = __builtin_bit_cast(bf16x8,
            *(const uint4*)(hb_base + (size_t)(tt0 + l15) * 256 + c * 32 + kq * 8));
#pragma unroll
      for (int jt = 0; jt < 3; ++jt) {
        f32x4 a2 = {bo3[jt], bo3[jt], bo3[jt], bo3[jt]};
#pragma unroll
        for (int c = 0; c < 8; ++c) {
          bf16x8 bfr = __builtin_bit_cast(bf16x8, *(const uint4*)&wfrag[jt][c][lane][0]);
          a2 = __builtin_amdgcn_mfma_f32_16x16x32_bf16(afr[c], bfr, a2, 0, 0, 0);
        }
#pragma unroll
        for (int r = 0; r < 4; ++r)
          dst[ts * 16 + kq * 4 + r][jt * 16 + l15] = a2[r];
      }
    }
  };

  // wave1 producer state (masks for numerator + cnt)
  unsigned long long nb4 = 0, nb5 = 0, nb6 = 0, nb7 = 0;
  float snum = 0.f;
  if (wv == 1) {
    nb4 = __ballot(words[b * 512 + 4 * 64 + lane] != 0);
    nb5 = __ballot(words[b * 512 + 5 * 64 + lane] != 0);
    nb6 = __ballot(words[b * 512 + 6 * 64 + lane] != 0);
    nb7 = __ballot(words[b * 512 + 7 * 64 + lane] != 0);
    produce(0, tA[0]);
    produce(7, tB[0]);
  }
  __syncthreads();   // first tiles ready

  // ---- chain inits (wave0 holds BOTH chains) ----
  float d_a = 0.f, Ecur_a = 0.f, d_b = 0.f, Ecur_b = 0.f;
  int S_a = 0, ep_a = 0, S_b = 0, ep_b = 0;
  if (wv == 0) {
    d_a = v ? fexp2((st[j] + tA[0][0][jj]) * L2E) : 0.f;   // alpha_0
    Ecur_a = fexp2(tA[0][1][jj] * L2E);                    // E_1
    d_b = v ? fexp2(et[j] * L2E) : 0.f;                    // w = exp(et)
    Ecur_b = fexp2(tB[0][63][jj] * L2E);                   // E_511
  }

#pragma unroll 1
  for (int p = 0; p < 4; ++p) {
    if (wv == 0) {
      // ---- dual serial chains, step-interleaved, all emis from LDS ----
      const unsigned long long mq =
          (p == 0) ? mq7 : (p == 1) ? mq6 : (p == 2) ? mq5 : mq4;
      if (p > 0) {  // refresh look-ahead E (last in-phase body's was dummy)
        Ecur_a = fexp2(EMA(64 * p) * L2E);
        Ecur_b = fexp2(EMB(511 - 64 * p) * L2E);
      }
      if (p == 0) {
        // gi=0: alpha peel t=1..7 interleaved with beta group t=511..504
        const uint_t mm = (uint_t)(mq >> 56);
        A_BODY(false, 2, false)
        B_BODY(false, 510, (mm >> 7) & 1u, true)
        A_BODY(true,  3, false)
        B_BODY(false, 509, (mm >> 6) & 1u, false)
        A_BODY(false, 4, false)
        B_BODY(true,  508, (mm >> 5) & 1u, false)
        A_BODY(false, 5, false)
        B_BODY(false, 507, (mm >> 4) & 1u, false)
        A_BODY(false, 6, false)
        B_BODY(false, 506, (mm >> 3) & 1u, false)
        A_BODY(false, 7, false)
        B_BODY(false, 505, (mm >> 2) & 1u, false)
        A_BODY(false, 8, false)
        B_BODY(false, 504, (mm >> 1) & 1u, false)
        B_BODY(false, 503, (mm >> 0) & 1u, false)
      }
#pragma unroll 1
      for (int gi = (p == 0) ? 1 : 0; gi < 8; ++gi) {
        const int G = p * 64 + gi * 8;
        const int T0 = 511 - p * 64 - gi * 8;
        const uint_t mm = (uint_t)(mq >> (56 - 8 * gi));
        const int ALAST = (gi == 7) ? (p * 64 + 63) : (G + 8);   // in-tile
        const int BLAST = (gi == 7) ? (448 - p * 64) : (T0 - 8); // in-tile
        GROUP_PAIR(G, T0, mm)
      }
    } else {
      // ---- producer: next tiles for both ends + numerator for current ----
      if (p < 3) {
        produce(p + 1, tA[(p + 1) & 1]);
        produce(6 - p, tB[((6 - p) & 1) ^ 1]);
      }
      {  // numerator A-side (t = 64p + lane, always active)
        const int t = p * 64 + lane;
        const int tg = tags[b * 512 + t];
        if (t == 0) {
          snum += st[tg] + tA[0][0][tg];
        } else {
          const int tp = tags[b * 512 + t - 1];
          snum += trans[tp * 48 + tg] + tA[p & 1][lane][tg];
        }
      }
      {  // numerator B-side (tile 7-p, masked)
        const int tl = 7 - p;
        const int t = tl * 64 + lane;
        const unsigned long long mqq =
            (p == 0) ? nb7 : (p == 1) ? nb6 : (p == 2) ? nb5 : nb4;
        if ((mqq >> lane) & 1ull) {
          const int tg = tags[b * 512 + t];
          const int tp = tags[b * 512 + t - 1];
          snum += trans[tp * 48 + tg] + tB[(tl & 1) ^ 1][lane][tg];
        }
      }
    }
    __syncthreads();
  }

  // ---- epilogue ----
  if (wv == 1) {
    float sr = snum;
#pragma unroll
    for (int dd = 32; dd; dd >>= 1) sr += __shfl_xor(sr, dd, 64);
    if (lane == 0) {
      const int cnt = 256 + (int)(__popcll(nb4) + __popcll(nb5) +
                                  __popcll(nb6) + __popcll(nb7));
      const int lt = tags[b * 512 + cnt - 1];
      res1[0] = sr + et[lt];
    }
  }
  __syncthreads();
  if (wv == 0) {
    float uf = d_a * d_b;   // x_j * y_j (0 on invalid lanes)
#pragma unroll
    for (int dd = 32; dd; dd >>= 1) uf += __shfl_xor(uf, dd, 64);
    if (lane == 0) {
      const float denom = ((float)(S_a + S_b) + flog2(uf)) * LN2;
      atomicAdd(out, (denom - res1[0]) * (1.0f / 256.0f));
    }
  }
}

// ---------------------------------------------------------------------------
extern "C" void kernel_launch(void* const* d_in, const int* in_sizes, int n_in,
                              void* d_out, int out_size, void* d_ws, size_t ws_size,
                              hipStream_t stream) {
  (void)in_sizes; (void)n_in; (void)out_size; (void)ws_size;
  const int*   words = (const int*)d_in[0];
  const int*   tags  = (const int*)d_in[1];
  // d_in[2] = mask (bool) -- unused; reconstructed as words != 0
  const float* emb   = (const float*)d_in[3];
  const float* Wih_f = (const float*)d_in[4];
  const float* Whh_f = (const float*)d_in[5];
  const float* bih_f = (const float*)d_in[6];
  const float* bhh_f = (const float*)d_in[7];
  const float* Wih_b = (const float*)d_in[8];
  const float* Whh_b = (const float*)d_in[9];
  const float* bih_b = (const float*)d_in[10];
  const float* bhh_b = (const float*)d_in[11];
  const float* Wout  = (const float*)d_in[12];
  const float* bout  = (const float*)d_in[13];
  const float* trans = (const float*)d_in[14];
  const float* st    = (const float*)d_in[15];
  const float* et    = (const float*)d_in[16];

  char* ws = (char*)d_ws;
  ushort_t* h_T = (ushort_t*)(ws);   // [256 b][512 t][256 k] bf16 = 64 MB

  k2_lstm  <<<256, 512, 0, stream>>>(words, emb,
                                     Wih_f, Whh_f, bih_f, bhh_f,
                                     Wih_b, Whh_b, bih_b, bhh_b,
                                     h_T, (float*)d_out);
  k4_fused <<<256, 128, 0, stream>>>(words, tags, h_T, Wout, bout,
                                     trans, st, et, (float*)d_out);
}